// Round 3
// baseline (584.266 us; speedup 1.0000x reference)
//
#include <hip/hip_runtime.h>
#include <hip/hip_cooperative_groups.h>
#include <cstdint>
#include <climits>
#include <cstddef>

namespace cg = cooperative_groups;
typedef unsigned long long u64;

#define B_ROWS 65536
#define BN_EPS 1e-5

// ---------------------------------------------------------------------------
// prep_kernel: pack all weights (once) + zero stat accumulators.
// w0: float4-interleaved order (word 4*cg+e, bit l <-> col cg*256+4l+e; tail
// word 12 = 4-bit nibbles). w1..w3: natural order [k][c]. w4: [c][k].
// ---------------------------------------------------------------------------
__global__ __launch_bounds__(256) void prep_kernel(
    const float* __restrict__ w0, const float* __restrict__ w1,
    const float* __restrict__ w2, const float* __restrict__ w3,
    const float* __restrict__ w4,
    u64* __restrict__ wb0T, u64* __restrict__ wbT, u64* __restrict__ w4b,
    long long* gsum, long long* gsq, int* gmin, int* gmax, double* colsum)
{
    const int lane = threadIdx.x & 63;
    const int wv   = threadIdx.x >> 6;
    const int b    = blockIdx.x;

    if (b < 64) {
        const int c = b * 4 + wv;                       // 0..255
        const float4* row = (const float4*)(w0 + (size_t)c * 784);
#pragma unroll
        for (int cg4 = 0; cg4 < 3; ++cg4) {
            const float4 f = row[cg4 * 64 + lane];
            const u64 e0 = __ballot(f.x >= 0.0f);
            const u64 e1 = __ballot(f.y >= 0.0f);
            const u64 e2 = __ballot(f.z >= 0.0f);
            const u64 e3 = __ballot(f.w >= 0.0f);
            if (lane == 0) {
                wb0T[(cg4*4+0)*256 + c] = e0;
                wb0T[(cg4*4+1)*256 + c] = e1;
                wb0T[(cg4*4+2)*256 + c] = e2;
                wb0T[(cg4*4+3)*256 + c] = e3;
            }
        }
        float4 f = make_float4(-1.f, -1.f, -1.f, -1.f);
        if (lane < 4) f = row[192 + lane];
        const u64 e0 = __ballot(f.x >= 0.0f) & 0xF;
        const u64 e1 = __ballot(f.y >= 0.0f) & 0xF;
        const u64 e2 = __ballot(f.z >= 0.0f) & 0xF;
        const u64 e3 = __ballot(f.w >= 0.0f) & 0xF;
        if (lane == 0) wb0T[12*256 + c] = e0 | (e1 << 4) | (e2 << 8) | (e3 << 12);
    } else if (b < 256) {
        const int idx = (b - 64) * 4 + wv;              // 0..767
        const int L = idx >> 8, c = idx & 255;
        const float* ws = (L == 0) ? w1 : (L == 1) ? w2 : w3;
#pragma unroll
        for (int k = 0; k < 4; ++k) {
            const u64 m = __ballot(ws[(size_t)c * 256 + k*64 + lane] >= 0.0f);
            if (lane == 0) wbT[L*1024 + k*256 + c] = m;
        }
    } else {
        for (int c = wv; c < 10; c += 4)
#pragma unroll
            for (int k = 0; k < 4; ++k) {
                const u64 m = __ballot(w4[(size_t)c * 256 + k*64 + lane] >= 0.0f);
                if (lane == 0) w4b[c*4 + k] = m;
            }
        for (int i = threadIdx.x; i < 1040; i += 256) { gsum[i] = 0; gsq[i] = 0; }
        if (threadIdx.x < 10) {
            gmin[threadIdx.x] = INT_MAX;
            gmax[threadIdx.x] = INT_MIN;
            colsum[threadIdx.x] = 0.0;
        }
    }
}

// ---------------------------------------------------------------------------
// do_layer: one binarized layer for this block's 256 rows.
// Per-thread 8x8 tile: rt=tid&31 -> rows rt+32j, ct=tid>>5 -> cols ct*8..+7.
// A: 8x ds_read_b64 stride-8B conflict-free; W: 4x ds_read_b128 broadcast.
// Stats: exact int sum/sumsq -> 32-lane shuffle reduce -> global i64 atomics
// -> grid.sync -> exact integer threshold -> byte-wise repack into dst.
// ---------------------------------------------------------------------------
template<int KW>
__device__ __forceinline__ void do_layer(const u64* __restrict__ sA,
    const u64* __restrict__ sW, int K,
    long long* gsumL, long long* gsqL,
    const float* __restrict__ ga, const float* __restrict__ be,
    u64* __restrict__ dst, int* sSgn, int* sThr, cg::grid_group& grid)
{
    const int tid = threadIdx.x;
    const int rt = tid & 31;
    const int ct = tid >> 5;
    const int c0 = ct << 3;

    int p[8][8];
#pragma unroll
    for (int i = 0; i < 8; ++i)
#pragma unroll
        for (int j = 0; j < 8; ++j) p[i][j] = 0;

#pragma unroll 1
    for (int k = 0; k < KW; ++k) {
        u64 a[8], w[8];
#pragma unroll
        for (int j = 0; j < 8; ++j) a[j] = sA[k*256 + rt + 32*j];
#pragma unroll
        for (int j = 0; j < 4; ++j) {
            const ulonglong2 t = *(const ulonglong2*)(sW + k*256 + c0 + 2*j);
            w[2*j] = t.x; w[2*j+1] = t.y;
        }
#pragma unroll
        for (int jr = 0; jr < 8; ++jr)
#pragma unroll
            for (int jc = 0; jc < 8; ++jc)
                p[jr][jc] += (int)__popcll(a[jr] ^ w[jc]);
    }

    // exact per-column block stats (int: 256*784^2 < 2^31)
    int s[8], q[8];
#pragma unroll
    for (int jc = 0; jc < 8; ++jc) {
        int ss = 0, qq = 0;
#pragma unroll
        for (int jr = 0; jr < 8; ++jr) {
            const int v = K - 2*p[jr][jc];
            ss += v; qq += v*v;
        }
        s[jc] = ss; q[jc] = qq;
    }
#pragma unroll
    for (int m = 1; m < 32; m <<= 1)
#pragma unroll
        for (int jc = 0; jc < 8; ++jc) {
            s[jc] += __shfl_xor(s[jc], m);
            q[jc] += __shfl_xor(q[jc], m);
        }
    if ((tid & 31) == 0) {
#pragma unroll
        for (int jc = 0; jc < 8; ++jc) {
            atomicAdd((u64*)&gsumL[c0+jc], (u64)(long long)s[jc]);
            atomicAdd((u64*)&gsqL[c0+jc],  (u64)(long long)q[jc]);
        }
    }
    grid.sync();

    if (tid < 256) {
        const long long sv = __hip_atomic_load(&gsumL[tid], __ATOMIC_RELAXED, __HIP_MEMORY_SCOPE_AGENT);
        const long long qv = __hip_atomic_load(&gsqL[tid],  __ATOMIC_RELAXED, __HIP_MEMORY_SCOPE_AGENT);
        const double mean = (double)sv / (double)B_ROWS;
        double var = (double)qv / (double)B_ROWS - mean * mean;
        if (var < 0.0) var = 0.0;
        const double rs    = 1.0 / sqrt(var + BN_EPS);
        const double scale = (double)ga[tid] * rs;
        const double bt    = (double)be[tid];
        int sg, t;
        if (scale > 0.0) {
            double tt = mean - bt / scale; tt = fmin(fmax(tt, -1e6), 1e6);
            sg = 1; t = (int)ceil(tt);
        } else if (scale < 0.0) {
            double tt = mean - bt / scale; tt = fmin(fmax(tt, -1e6), 1e6);
            sg = -1; t = (int)(-floor(tt));
        } else { sg = 0; t = (bt >= 0.0) ? INT_MIN : 1; }
        sSgn[tid] = sg; sThr[tid] = t;
    }
    __syncthreads();

    const int wI = ct >> 3;
    const int bI = ct & 7;
    int sg[8], th[8];
#pragma unroll
    for (int jc = 0; jc < 8; ++jc) { sg[jc] = sSgn[c0+jc]; th[jc] = sThr[c0+jc]; }
#pragma unroll
    for (int jr = 0; jr < 8; ++jr) {
        const int r = rt + 32*jr;
        unsigned byteV = 0;
#pragma unroll
        for (int jc = 0; jc < 8; ++jc) {
            const int v = K - 2*p[jr][jc];
            byteV |= (unsigned)(sg[jc]*v >= th[jc]) << jc;
        }
        ((unsigned char*)dst)[(size_t)(wI*256 + r)*8 + bI] = (unsigned char)byteV;
    }
    __syncthreads();
}

// ---------------------------------------------------------------------------
// fused_kernel: whole network. 256 blocks x 1024 threads, 1 block/CU.
// Block owns 256 rows; activations live in LDS; v in registers across syncs.
// ---------------------------------------------------------------------------
__global__ __launch_bounds__(1024, 4) void fused_kernel(
    const float* __restrict__ x,
    const u64* __restrict__ wb0T, const u64* __restrict__ wbT, const u64* __restrict__ w4b,
    const float* __restrict__ g0, const float* __restrict__ g1, const float* __restrict__ g2,
    const float* __restrict__ g3, const float* __restrict__ g4,
    const float* __restrict__ b0, const float* __restrict__ b1, const float* __restrict__ b2,
    const float* __restrict__ b3, const float* __restrict__ b4,
    long long* gsum, long long* gsq, int* gmin, int* gmax, double* colsum,
    float* __restrict__ out)
{
    __shared__ __align__(16) u64 sA0[13*256];
    __shared__ __align__(16) u64 sW[13*256];
    __shared__ __align__(16) u64 sB0[4*256];
    __shared__ __align__(16) u64 sB1[4*256];
    __shared__ int sSgn[256], sThr[256];
    __shared__ short sV4[256*10];
    __shared__ u64 sW4[40];
    __shared__ double spart[320];
    __shared__ double sZs[10], sZb[10], sCsum[10];

    cg::grid_group grid = cg::this_grid();
    const int tid  = threadIdx.x;
    const int lane = tid & 63;
    const int wv   = tid >> 6;
    const int blk  = blockIdx.x;

    // ---- pack x (binarize x-0.5 >= 0, float4-interleaved word order) ----
    for (int i = 0; i < 16; ++i) {
        const int r = wv * 16 + i;
        const float4* xr = (const float4*)(x + (size_t)(blk*256 + r) * 784);
#pragma unroll
        for (int cg4 = 0; cg4 < 3; ++cg4) {
            const float4 f = xr[cg4*64 + lane];
            const u64 e0 = __ballot(f.x >= 0.5f);
            const u64 e1 = __ballot(f.y >= 0.5f);
            const u64 e2 = __ballot(f.z >= 0.5f);
            const u64 e3 = __ballot(f.w >= 0.5f);
            if (lane == 0) {
                sA0[(cg4*4+0)*256 + r] = e0;
                sA0[(cg4*4+1)*256 + r] = e1;
                sA0[(cg4*4+2)*256 + r] = e2;
                sA0[(cg4*4+3)*256 + r] = e3;
            }
        }
        float4 f = make_float4(-1.f, -1.f, -1.f, -1.f);
        if (lane < 4) f = xr[192 + lane];
        const u64 e0 = __ballot(f.x >= 0.5f) & 0xF;
        const u64 e1 = __ballot(f.y >= 0.5f) & 0xF;
        const u64 e2 = __ballot(f.z >= 0.5f) & 0xF;
        const u64 e3 = __ballot(f.w >= 0.5f) & 0xF;
        if (lane == 0) sA0[12*256 + r] = e0 | (e1 << 4) | (e2 << 8) | (e3 << 12);
    }
    __syncthreads();

    // ---- layer 0 (K=784, 13 words) ----
    for (int i = tid; i < 13*256; i += 1024) sW[i] = wb0T[i];
    __syncthreads();
    do_layer<13>(sA0, sW, 784, gsum, gsq, g0, b0, sB0, sSgn, sThr, grid);

    // ---- layers 1..3 (K=256, 4 words) ----
    const float* gam[4] = { nullptr, g1, g2, g3 };
    const float* bet[4] = { nullptr, b1, b2, b3 };
    u64* cur = sB0; u64* nxt = sB1;
    for (int L = 1; L <= 3; ++L) {
        sW[tid] = wbT[(L-1)*1024 + tid];
        __syncthreads();
        do_layer<4>(cur, sW, 256, gsum + L*256, gsq + L*256, gam[L], bet[L],
                    nxt, sSgn, sThr, grid);
        u64* t = cur; cur = nxt; nxt = t;
    }

    // ---- layer 4 (K=256 -> 10 cols) + exact stats ----
    if (tid < 40) sW4[tid] = w4b[tid];
    __syncthreads();
    long long* gsum4 = gsum + 1024;
    long long* gsq4  = gsq  + 1024;
    if (tid < 256) {
        const int r = tid;
        const u64 a0 = cur[0*256+r], a1 = cur[1*256+r], a2 = cur[2*256+r], a3 = cur[3*256+r];
        int vr[10];
#pragma unroll
        for (int c = 0; c < 10; ++c) {
            const int pp = (int)__popcll(a0 ^ sW4[c*4+0]) + (int)__popcll(a1 ^ sW4[c*4+1])
                         + (int)__popcll(a2 ^ sW4[c*4+2]) + (int)__popcll(a3 ^ sW4[c*4+3]);
            vr[c] = 256 - 2*pp;
            sV4[r*10 + c] = (short)vr[c];
        }
#pragma unroll
        for (int c = 0; c < 10; ++c) {
            int ss = vr[c], qq = vr[c]*vr[c], mn = vr[c], mx = vr[c];
#pragma unroll
            for (int m = 1; m < 64; m <<= 1) {
                ss += __shfl_xor(ss, m);
                qq += __shfl_xor(qq, m);
                mn = min(mn, __shfl_xor(mn, m));
                mx = max(mx, __shfl_xor(mx, m));
            }
            if ((tid & 63) == 0) {
                atomicAdd((u64*)&gsum4[c], (u64)(long long)ss);
                atomicAdd((u64*)&gsq4[c],  (u64)(long long)qq);
                atomicMin(&gmin[c], mn);
                atomicMax(&gmax[c], mx);
            }
        }
    }
    grid.sync();

    // ---- BN affine + exact column-max shift (redundant per block) ----
    if (tid < 10) {
        const long long sv = __hip_atomic_load(&gsum4[tid], __ATOMIC_RELAXED, __HIP_MEMORY_SCOPE_AGENT);
        const long long qv = __hip_atomic_load(&gsq4[tid],  __ATOMIC_RELAXED, __HIP_MEMORY_SCOPE_AGENT);
        const int mn = __hip_atomic_load(&gmin[tid], __ATOMIC_RELAXED, __HIP_MEMORY_SCOPE_AGENT);
        const int mx = __hip_atomic_load(&gmax[tid], __ATOMIC_RELAXED, __HIP_MEMORY_SCOPE_AGENT);
        const double mean = (double)sv / (double)B_ROWS;
        double var = (double)qv / (double)B_ROWS - mean * mean;
        if (var < 0.0) var = 0.0;
        const double rs    = 1.0 / sqrt(var + BN_EPS);
        const double scale = (double)g4[tid] * rs;
        const double bias  = (double)b4[tid] - mean * scale;
        const double z1 = scale * (double)mn + bias;
        const double z2 = scale * (double)mx + bias;
        sZs[tid] = scale;
        sZb[tid] = bias - fmax(z1, z2);
    }
    __syncthreads();

    // ---- softmax over batch: per-block partial colsums ----
    if (tid < 320) {
        const int c = tid % 10;
        const int g = tid / 10;
        const double zs_ = sZs[c], zb_ = sZb[c];
        double acc = 0.0;
#pragma unroll
        for (int j = 0; j < 8; ++j) {
            const int r = g + 32*j;
            acc += exp(zs_ * (double)sV4[r*10 + c] + zb_);
        }
        spart[c*32 + g] = acc;
    }
    __syncthreads();
    if (tid < 10) {
        double a = 0.0;
        for (int g = 0; g < 32; ++g) a += spart[tid*32 + g];
        atomicAdd(&colsum[tid], a);
    }
    grid.sync();

    if (tid < 10) sCsum[tid] = __hip_atomic_load(&colsum[tid], __ATOMIC_RELAXED, __HIP_MEMORY_SCOPE_AGENT);
    __syncthreads();

    if (tid < 256) {
        const int r = tid;
#pragma unroll
        for (int c = 0; c < 10; ++c) {
            const double e = exp(sZs[c] * (double)sV4[r*10 + c] + sZb[c]);
            out[(size_t)(blk*256 + r)*10 + c] = (float)(e / sCsum[c]);
        }
    }
}

// ---------------------------------------------------------------------------
extern "C" void kernel_launch(void* const* d_in, const int* in_sizes, int n_in,
                              void* d_out, int out_size, void* d_ws, size_t ws_size,
                              hipStream_t stream)
{
    const float* x  = (const float*)d_in[0];
    const float* w0 = (const float*)d_in[1];
    const float* w1 = (const float*)d_in[4];
    const float* w2 = (const float*)d_in[7];
    const float* w3 = (const float*)d_in[10];
    const float* w4 = (const float*)d_in[13];
    const float* g0 = (const float*)d_in[2];
    const float* g1 = (const float*)d_in[5];
    const float* g2 = (const float*)d_in[8];
    const float* g3 = (const float*)d_in[11];
    const float* g4 = (const float*)d_in[14];
    const float* b0 = (const float*)d_in[3];
    const float* b1 = (const float*)d_in[6];
    const float* b2 = (const float*)d_in[9];
    const float* b3 = (const float*)d_in[12];
    const float* b4 = (const float*)d_in[15];

    char* p = (char*)d_ws;
    auto alloc = [&](size_t bytes) -> char* {
        char* r = p;
        p += (bytes + 255) & ~(size_t)255;
        return r;
    };
    u64*       wb0T   = (u64*)alloc(13*256*8);
    u64*       wbT    = (u64*)alloc(3*1024*8);
    u64*       w4b    = (u64*)alloc(40*8);
    long long* gsum   = (long long*)alloc(1040*8);
    long long* gsq    = (long long*)alloc(1040*8);
    int*       gmin   = (int*)alloc(16*4);
    int*       gmax   = (int*)alloc(16*4);
    double*    colsum = (double*)alloc(16*8);
    float*     out    = (float*)d_out;

    prep_kernel<<<257, 256, 0, stream>>>(w0, w1, w2, w3, w4, wb0T, wbT, w4b,
                                         gsum, gsq, gmin, gmax, colsum);

    void* args[] = {
        (void*)&x, (void*)&wb0T, (void*)&wbT, (void*)&w4b,
        (void*)&g0, (void*)&g1, (void*)&g2, (void*)&g3, (void*)&g4,
        (void*)&b0, (void*)&b1, (void*)&b2, (void*)&b3, (void*)&b4,
        (void*)&gsum, (void*)&gsq, (void*)&gmin, (void*)&gmax, (void*)&colsum,
        (void*)&out
    };
    (void)hipLaunchCooperativeKernel((void*)fused_kernel, dim3(256), dim3(1024),
                                     args, 0, stream);
}

// Round 4
// 574.699 us; speedup vs baseline: 1.0166x; 1.0166x over previous
//
#include <hip/hip_runtime.h>
#include <cstdint>
#include <climits>
#include <cstddef>

typedef unsigned long long u64;

#define B_ROWS 65536
#define NBLK   256
#define BN_EPS 1e-5

// ---------------------------------------------------------------------------
// prep_kernel: pack all weights (once per launch) + zero stat accumulators
// and the grid-barrier counter.
// w0: float4-interleaved order (word 4*cg+e, bit l <-> col cg*256+4l+e; tail
// word 12 = 4-bit nibbles). w1..w3: natural order [k][c]. w4: [c][k].
// ---------------------------------------------------------------------------
__global__ __launch_bounds__(256) void prep_kernel(
    const float* __restrict__ w0, const float* __restrict__ w1,
    const float* __restrict__ w2, const float* __restrict__ w3,
    const float* __restrict__ w4,
    u64* __restrict__ wb0T, u64* __restrict__ wbT, u64* __restrict__ w4b,
    long long* gsum, long long* gsq, int* gmin, int* gmax, double* colsum,
    unsigned* cnt)
{
    const int lane = threadIdx.x & 63;
    const int wv   = threadIdx.x >> 6;
    const int b    = blockIdx.x;

    if (b < 64) {
        const int c = b * 4 + wv;                       // 0..255
        const float4* row = (const float4*)(w0 + (size_t)c * 784);
#pragma unroll
        for (int cg4 = 0; cg4 < 3; ++cg4) {
            const float4 f = row[cg4 * 64 + lane];
            const u64 e0 = __ballot(f.x >= 0.0f);
            const u64 e1 = __ballot(f.y >= 0.0f);
            const u64 e2 = __ballot(f.z >= 0.0f);
            const u64 e3 = __ballot(f.w >= 0.0f);
            if (lane == 0) {
                wb0T[(cg4*4+0)*256 + c] = e0;
                wb0T[(cg4*4+1)*256 + c] = e1;
                wb0T[(cg4*4+2)*256 + c] = e2;
                wb0T[(cg4*4+3)*256 + c] = e3;
            }
        }
        float4 f = make_float4(-1.f, -1.f, -1.f, -1.f);
        if (lane < 4) f = row[192 + lane];
        const u64 e0 = __ballot(f.x >= 0.0f) & 0xF;
        const u64 e1 = __ballot(f.y >= 0.0f) & 0xF;
        const u64 e2 = __ballot(f.z >= 0.0f) & 0xF;
        const u64 e3 = __ballot(f.w >= 0.0f) & 0xF;
        if (lane == 0) wb0T[12*256 + c] = e0 | (e1 << 4) | (e2 << 8) | (e3 << 12);
    } else if (b < 256) {
        const int idx = (b - 64) * 4 + wv;              // 0..767
        const int L = idx >> 8, c = idx & 255;
        const float* ws = (L == 0) ? w1 : (L == 1) ? w2 : w3;
#pragma unroll
        for (int k = 0; k < 4; ++k) {
            const u64 m = __ballot(ws[(size_t)c * 256 + k*64 + lane] >= 0.0f);
            if (lane == 0) wbT[L*1024 + k*256 + c] = m;
        }
    } else {
        for (int c = wv; c < 10; c += 4)
#pragma unroll
            for (int k = 0; k < 4; ++k) {
                const u64 m = __ballot(w4[(size_t)c * 256 + k*64 + lane] >= 0.0f);
                if (lane == 0) w4b[c*4 + k] = m;
            }
        for (int i = threadIdx.x; i < 1040; i += 256) { gsum[i] = 0; gsq[i] = 0; }
        if (threadIdx.x < 10) {
            gmin[threadIdx.x] = INT_MAX;
            gmax[threadIdx.x] = INT_MIN;
            colsum[threadIdx.x] = 0.0;
        }
        if (threadIdx.x == 0) *cnt = 0u;
    }
}

// ---------------------------------------------------------------------------
// grid_barrier: epoch-based single-counter barrier. __syncthreads drains this
// block's stat atomics (compiler emits vmcnt(0) before s_barrier), thread 0
// does an acq-rel arrive + acquire spin, second __syncthreads releases block.
// ---------------------------------------------------------------------------
__device__ __forceinline__ void grid_barrier(unsigned* cnt, int* sEpoch)
{
    __syncthreads();
    if (threadIdx.x == 0) {
        const unsigned target = (unsigned)(++(*sEpoch)) * (unsigned)NBLK;
        __hip_atomic_fetch_add(cnt, 1u, __ATOMIC_ACQ_REL, __HIP_MEMORY_SCOPE_AGENT);
        while (__hip_atomic_load(cnt, __ATOMIC_ACQUIRE, __HIP_MEMORY_SCOPE_AGENT) < target)
            __builtin_amdgcn_s_sleep(2);
    }
    __syncthreads();
}

// ---------------------------------------------------------------------------
// do_layer: one binarized layer for this block's 256 rows, 512 threads.
// Per-thread tile: 8 rows (rt=tid&31, rows rt+32j) x 16 cols (ct=tid>>5,
// cols ct*16..+15), popcounts PACKED 2 cols/u32 (<=832 < 2^16, no carry).
// A: 8x ds_read_b64 stride-8B (2-way, free); W: 8x ds_read_b128 broadcast.
// Stats: exact int sum/sumsq -> 32-lane shuffle reduce -> global i64 atomics
// -> grid barrier -> exact integer threshold -> 16-bit halfword repack.
// ---------------------------------------------------------------------------
template<int KW>
__device__ __forceinline__ void do_layer(const u64* __restrict__ sA,
    const u64* __restrict__ sW, int K,
    long long* gsumL, long long* gsqL,
    const float* __restrict__ ga, const float* __restrict__ be,
    u64* __restrict__ dst, int* sSgn, int* sThr, unsigned* cnt, int* sEpoch)
{
    const int tid = threadIdx.x;
    const int rt  = tid & 31;
    const int ct  = tid >> 5;          // 0..15
    const int c0  = ct << 4;           // first of 16 columns

    unsigned p2[8][8];                 // [row][colpair], lo16=col 2e, hi16=col 2e+1
#pragma unroll
    for (int i = 0; i < 8; ++i)
#pragma unroll
        for (int j = 0; j < 8; ++j) p2[i][j] = 0;

#pragma unroll 1
    for (int k = 0; k < KW; ++k) {
        u64 a[8];
#pragma unroll
        for (int j = 0; j < 8; ++j) a[j] = sA[k*256 + rt + 32*j];
#pragma unroll
        for (int e = 0; e < 8; ++e) {
            const ulonglong2 wp = *(const ulonglong2*)(sW + k*256 + c0 + 2*e);
#pragma unroll
            for (int jr = 0; jr < 8; ++jr) {
                const unsigned b0 = (unsigned)__popcll(a[jr] ^ wp.x);
                const unsigned b1 = (unsigned)__popcll(a[jr] ^ wp.y);
                p2[jr][e] += b0 + (b1 << 16);
            }
        }
    }

    // exact per-column stats for this thread's 8 rows x 16 cols
    int s[16], q[16];
#pragma unroll
    for (int e = 0; e < 8; ++e) {
        int s0 = 0, q0 = 0, s1 = 0, q1 = 0;
#pragma unroll
        for (int jr = 0; jr < 8; ++jr) {
            const int v0 = K - 2 * (int)(p2[jr][e] & 0xFFFFu);
            const int v1 = K - 2 * (int)(p2[jr][e] >> 16);
            s0 += v0; q0 += v0*v0;
            s1 += v1; q1 += v1*v1;
        }
        s[2*e] = s0; q[2*e] = q0; s[2*e+1] = s1; q[2*e+1] = q1;
    }
    // reduce over the 32 lanes sharing these columns (lane group aligned)
#pragma unroll
    for (int m = 1; m < 32; m <<= 1)
#pragma unroll
        for (int b = 0; b < 16; ++b) {
            s[b] += __shfl_xor(s[b], m);
            q[b] += __shfl_xor(q[b], m);
        }
    if (rt == 0) {
#pragma unroll
        for (int b = 0; b < 16; ++b) {
            atomicAdd((u64*)&gsumL[c0+b], (u64)(long long)s[b]);
            atomicAdd((u64*)&gsqL[c0+b],  (u64)(long long)q[b]);
        }
    }
    grid_barrier(cnt, sEpoch);

    // exact integer threshold per column (redundant per block, 256 threads)
    if (tid < 256) {
        const long long sv = __hip_atomic_load(&gsumL[tid], __ATOMIC_RELAXED, __HIP_MEMORY_SCOPE_AGENT);
        const long long qv = __hip_atomic_load(&gsqL[tid],  __ATOMIC_RELAXED, __HIP_MEMORY_SCOPE_AGENT);
        const double mean = (double)sv / (double)B_ROWS;
        double var = (double)qv / (double)B_ROWS - mean * mean;
        if (var < 0.0) var = 0.0;
        const double rs    = 1.0 / sqrt(var + BN_EPS);
        const double scale = (double)ga[tid] * rs;
        const double bt    = (double)be[tid];
        int sg, t;
        if (scale > 0.0) {
            double tt = mean - bt / scale; tt = fmin(fmax(tt, -1e6), 1e6);
            sg = 1; t = (int)ceil(tt);
        } else if (scale < 0.0) {
            double tt = mean - bt / scale; tt = fmin(fmax(tt, -1e6), 1e6);
            sg = -1; t = (int)(-floor(tt));
        } else { sg = 0; t = (bt >= 0.0) ? INT_MIN : 1; }
        sSgn[tid] = sg; sThr[tid] = t;
    }
    __syncthreads();

    // binarize + repack: this thread owns 16 consecutive bits (halfword ct&3)
    // of output word ct>>2 for each of its 8 rows.
    int sg[16], th[16];
#pragma unroll
    for (int b = 0; b < 16; ++b) { sg[b] = sSgn[c0+b]; th[b] = sThr[c0+b]; }
    const int wI = ct >> 2;
    const int hI = ct & 3;
#pragma unroll
    for (int jr = 0; jr < 8; ++jr) {
        const int r = rt + 32*jr;
        unsigned mask16 = 0;
#pragma unroll
        for (int e = 0; e < 8; ++e) {
            const int v0 = K - 2 * (int)(p2[jr][e] & 0xFFFFu);
            const int v1 = K - 2 * (int)(p2[jr][e] >> 16);
            mask16 |= (unsigned)(sg[2*e]  *v0 >= th[2*e])   << (2*e);
            mask16 |= (unsigned)(sg[2*e+1]*v1 >= th[2*e+1]) << (2*e+1);
        }
        ((unsigned short*)dst)[(size_t)(wI*256 + r)*4 + hI] = (unsigned short)mask16;
    }
    __syncthreads();
}

// ---------------------------------------------------------------------------
// fused_kernel: whole network. 256 blocks x 512 threads, 1 block/CU.
// Block owns 256 rows; activations live in LDS; popcounts in registers.
// ---------------------------------------------------------------------------
__global__ __launch_bounds__(512, 2) void fused_kernel(
    const float* __restrict__ x,
    const u64* __restrict__ wb0T, const u64* __restrict__ wbT, const u64* __restrict__ w4b,
    const float* __restrict__ g0, const float* __restrict__ g1, const float* __restrict__ g2,
    const float* __restrict__ g3, const float* __restrict__ g4,
    const float* __restrict__ b0, const float* __restrict__ b1, const float* __restrict__ b2,
    const float* __restrict__ b3, const float* __restrict__ b4,
    long long* gsum, long long* gsq, int* gmin, int* gmax, double* colsum,
    unsigned* cnt, float* __restrict__ out)
{
    __shared__ __align__(16) u64 sA0[13*256];
    __shared__ __align__(16) u64 sW[13*256];
    __shared__ __align__(16) u64 sB0[4*256];
    __shared__ __align__(16) u64 sB1[4*256];
    __shared__ int sSgn[256], sThr[256];
    __shared__ short sV4[256*10];
    __shared__ u64 sW4[40];
    __shared__ double spart[320];
    __shared__ double sZs[10], sZb[10], sCsum[10];
    __shared__ int sEpoch;

    const int tid  = threadIdx.x;
    const int lane = tid & 63;
    const int wv   = tid >> 6;          // 0..7
    const int blk  = blockIdx.x;
    if (tid == 0) sEpoch = 0;

    // ---- pack x (binarize x-0.5 >= 0, float4-interleaved word order) ----
    for (int i = 0; i < 32; ++i) {
        const int r = wv * 32 + i;
        const float4* xr = (const float4*)(x + (size_t)(blk*256 + r) * 784);
#pragma unroll
        for (int cg4 = 0; cg4 < 3; ++cg4) {
            const float4 f = xr[cg4*64 + lane];
            const u64 e0 = __ballot(f.x >= 0.5f);
            const u64 e1 = __ballot(f.y >= 0.5f);
            const u64 e2 = __ballot(f.z >= 0.5f);
            const u64 e3 = __ballot(f.w >= 0.5f);
            if (lane == 0) {
                sA0[(cg4*4+0)*256 + r] = e0;
                sA0[(cg4*4+1)*256 + r] = e1;
                sA0[(cg4*4+2)*256 + r] = e2;
                sA0[(cg4*4+3)*256 + r] = e3;
            }
        }
        float4 f = make_float4(-1.f, -1.f, -1.f, -1.f);
        if (lane < 4) f = xr[192 + lane];
        const u64 e0 = __ballot(f.x >= 0.5f) & 0xF;
        const u64 e1 = __ballot(f.y >= 0.5f) & 0xF;
        const u64 e2 = __ballot(f.z >= 0.5f) & 0xF;
        const u64 e3 = __ballot(f.w >= 0.5f) & 0xF;
        if (lane == 0) sA0[12*256 + r] = e0 | (e1 << 4) | (e2 << 8) | (e3 << 12);
    }
    __syncthreads();

    // ---- layer 0 (K=784, 13 words) ----
    for (int i = tid; i < 13*256; i += 512) sW[i] = wb0T[i];
    __syncthreads();
    do_layer<13>(sA0, sW, 784, gsum, gsq, g0, b0, sB0, sSgn, sThr, cnt, &sEpoch);

    // ---- layers 1..3 (K=256, 4 words) ----
    const float* gam[4] = { nullptr, g1, g2, g3 };
    const float* bet[4] = { nullptr, b1, b2, b3 };
    u64* cur = sB0; u64* nxt = sB1;
    for (int L = 1; L <= 3; ++L) {
        for (int i = tid; i < 1024; i += 512) sW[i] = wbT[(L-1)*1024 + i];
        __syncthreads();
        do_layer<4>(cur, sW, 256, gsum + L*256, gsq + L*256, gam[L], bet[L],
                    nxt, sSgn, sThr, cnt, &sEpoch);
        u64* t = cur; cur = nxt; nxt = t;
    }

    // ---- layer 4 (K=256 -> 10 cols) + exact stats ----
    if (tid < 40) sW4[tid] = w4b[tid];
    __syncthreads();
    long long* gsum4 = gsum + 1024;
    long long* gsq4  = gsq  + 1024;
    if (tid < 256) {
        const int r = tid;
        const u64 a0 = cur[0*256+r], a1 = cur[1*256+r], a2 = cur[2*256+r], a3 = cur[3*256+r];
        int vr[10];
#pragma unroll
        for (int c = 0; c < 10; ++c) {
            const int pp = (int)__popcll(a0 ^ sW4[c*4+0]) + (int)__popcll(a1 ^ sW4[c*4+1])
                         + (int)__popcll(a2 ^ sW4[c*4+2]) + (int)__popcll(a3 ^ sW4[c*4+3]);
            vr[c] = 256 - 2*pp;
            sV4[r*10 + c] = (short)vr[c];
        }
#pragma unroll
        for (int c = 0; c < 10; ++c) {
            int ss = vr[c], qq = vr[c]*vr[c], mn = vr[c], mx = vr[c];
#pragma unroll
            for (int m = 1; m < 64; m <<= 1) {
                ss += __shfl_xor(ss, m);
                qq += __shfl_xor(qq, m);
                mn = min(mn, __shfl_xor(mn, m));
                mx = max(mx, __shfl_xor(mx, m));
            }
            if (lane == 0) {
                atomicAdd((u64*)&gsum4[c], (u64)(long long)ss);
                atomicAdd((u64*)&gsq4[c],  (u64)(long long)qq);
                atomicMin(&gmin[c], mn);
                atomicMax(&gmax[c], mx);
            }
        }
    }
    grid_barrier(cnt, &sEpoch);

    // ---- BN affine + exact column-max shift (redundant per block) ----
    if (tid < 10) {
        const long long sv = __hip_atomic_load(&gsum4[tid], __ATOMIC_RELAXED, __HIP_MEMORY_SCOPE_AGENT);
        const long long qv = __hip_atomic_load(&gsq4[tid],  __ATOMIC_RELAXED, __HIP_MEMORY_SCOPE_AGENT);
        const int mn = __hip_atomic_load(&gmin[tid], __ATOMIC_RELAXED, __HIP_MEMORY_SCOPE_AGENT);
        const int mx = __hip_atomic_load(&gmax[tid], __ATOMIC_RELAXED, __HIP_MEMORY_SCOPE_AGENT);
        const double mean = (double)sv / (double)B_ROWS;
        double var = (double)qv / (double)B_ROWS - mean * mean;
        if (var < 0.0) var = 0.0;
        const double rs    = 1.0 / sqrt(var + BN_EPS);
        const double scale = (double)g4[tid] * rs;
        const double bias  = (double)b4[tid] - mean * scale;
        const double z1 = scale * (double)mn + bias;
        const double z2 = scale * (double)mx + bias;
        sZs[tid] = scale;
        sZb[tid] = bias - fmax(z1, z2);
    }
    __syncthreads();

    // ---- softmax over batch: per-block partial colsums ----
    if (tid < 320) {
        const int c = tid % 10;
        const int g = tid / 10;
        const double zs_ = sZs[c], zb_ = sZb[c];
        double acc = 0.0;
#pragma unroll
        for (int j = 0; j < 8; ++j) {
            const int r = g + 32*j;
            acc += exp(zs_ * (double)sV4[r*10 + c] + zb_);
        }
        spart[c*32 + g] = acc;
    }
    __syncthreads();
    if (tid < 10) {
        double a = 0.0;
        for (int g = 0; g < 32; ++g) a += spart[tid*32 + g];
        atomicAdd(&colsum[tid], a);
    }
    grid_barrier(cnt, &sEpoch);

    if (tid < 10) sCsum[tid] = __hip_atomic_load(&colsum[tid], __ATOMIC_RELAXED, __HIP_MEMORY_SCOPE_AGENT);
    __syncthreads();

    if (tid < 256) {
        const int r = tid;
#pragma unroll
        for (int c = 0; c < 10; ++c) {
            const double e = exp(sZs[c] * (double)sV4[r*10 + c] + sZb[c]);
            out[(size_t)(blk*256 + r)*10 + c] = (float)(e / sCsum[c]);
        }
    }
}

// ---------------------------------------------------------------------------
extern "C" void kernel_launch(void* const* d_in, const int* in_sizes, int n_in,
                              void* d_out, int out_size, void* d_ws, size_t ws_size,
                              hipStream_t stream)
{
    const float* x  = (const float*)d_in[0];
    const float* w0 = (const float*)d_in[1];
    const float* w1 = (const float*)d_in[4];
    const float* w2 = (const float*)d_in[7];
    const float* w3 = (const float*)d_in[10];
    const float* w4 = (const float*)d_in[13];
    const float* g0 = (const float*)d_in[2];
    const float* g1 = (const float*)d_in[5];
    const float* g2 = (const float*)d_in[8];
    const float* g3 = (const float*)d_in[11];
    const float* g4 = (const float*)d_in[14];
    const float* b0 = (const float*)d_in[3];
    const float* b1 = (const float*)d_in[6];
    const float* b2 = (const float*)d_in[9];
    const float* b3 = (const float*)d_in[12];
    const float* b4 = (const float*)d_in[15];

    char* p = (char*)d_ws;
    auto alloc = [&](size_t bytes) -> char* {
        char* r = p;
        p += (bytes + 255) & ~(size_t)255;
        return r;
    };
    u64*       wb0T   = (u64*)alloc(13*256*8);
    u64*       wbT    = (u64*)alloc(3*1024*8);
    u64*       w4b    = (u64*)alloc(40*8);
    long long* gsum   = (long long*)alloc(1040*8);
    long long* gsq    = (long long*)alloc(1040*8);
    int*       gmin   = (int*)alloc(16*4);
    int*       gmax   = (int*)alloc(16*4);
    double*    colsum = (double*)alloc(16*8);
    unsigned*  cnt    = (unsigned*)alloc(256);
    float*     out    = (float*)d_out;

    prep_kernel<<<257, 256, 0, stream>>>(w0, w1, w2, w3, w4, wb0T, wbT, w4b,
                                         gsum, gsq, gmin, gmax, colsum, cnt);

    void* args[] = {
        (void*)&x, (void*)&wb0T, (void*)&wbT, (void*)&w4b,
        (void*)&g0, (void*)&g1, (void*)&g2, (void*)&g3, (void*)&g4,
        (void*)&b0, (void*)&b1, (void*)&b2, (void*)&b3, (void*)&b4,
        (void*)&gsum, (void*)&gsq, (void*)&gmin, (void*)&gmax, (void*)&colsum,
        (void*)&cnt, (void*)&out
    };
    (void)hipLaunchCooperativeKernel((void*)fused_kernel, dim3(NBLK), dim3(512),
                                     args, 0, stream);
}